// Round 1
// baseline (1069.355 us; speedup 1.0000x reference)
//
#include <hip/hip_runtime.h>

// segment_sum: out[n][64] += edge_w[e][64] for all e with edge0[e]==n.
// E = 1.25M edges, N = 100K nodes, F = 64 fp32 features.
// Memory-bound: 320 MB edge_w read + 25.6 MB out. Baseline: atomic scatter.

constexpr int FDIM = 64;

__global__ __launch_bounds__(256) void spmm_scatter(
    const int* __restrict__ edge0,
    const float4* __restrict__ w4,
    float* __restrict__ out,
    long long total)   // total = E * 16 threads (each thread: 1 float4 = 4 feats)
{
    long long stride = (long long)gridDim.x * blockDim.x;
    for (long long i = (long long)blockIdx.x * blockDim.x + threadIdx.x;
         i < total; i += stride) {
        int e = (int)(i >> 4);       // edge id
        int q = (int)(i & 15);       // float4 slot within the 64-feature row
        int idx = edge0[e];          // destination node (broadcast across 16 lanes via L1)
        float4 w = w4[i];            // w4 index == e*16 + q == i ; coalesced 1KB/wave
        float* p = out + (size_t)idx * FDIM + q * 4;
        // HW global_atomic_add_f32 (not CAS loop); out is 25.6MB -> L2-resident.
        unsafeAtomicAdd(p + 0, w.x);
        unsafeAtomicAdd(p + 1, w.y);
        unsafeAtomicAdd(p + 2, w.z);
        unsafeAtomicAdd(p + 3, w.w);
    }
}

extern "C" void kernel_launch(void* const* d_in, const int* in_sizes, int n_in,
                              void* d_out, int out_size, void* d_ws, size_t ws_size,
                              hipStream_t stream) {
    const int* edge = (const int*)d_in[0];          // (2, E) int32 row-major; row 0 = dst idx
    const float* edge_w = (const float*)d_in[1];    // (E, 64) fp32
    float* out = (float*)d_out;                     // (N, 64) fp32

    const int E = in_sizes[1] / FDIM;               // 1,250,000

    // Harness poisons d_out once (0xAA) and never re-zeros between replays:
    // we must zero every call. hipMemsetAsync is graph-capture legal.
    hipMemsetAsync(d_out, 0, (size_t)out_size * sizeof(float), stream);

    const long long total = (long long)E * (FDIM / 4);
    const int block = 256;
    const int grid = 4096;  // grid-stride; ~16 blocks/CU worth of waves in flight
    spmm_scatter<<<grid, block, 0, stream>>>(edge, (const float4*)edge_w, out, total);
}

// Round 2
// 250.338 us; speedup vs baseline: 4.2716x; 4.2716x over previous
//
#include <hip/hip_runtime.h>

// segment_sum: out[n][64] = sum of edge_w[e][64] over e with edge0[e]==n.
// N = 100K, E = 1.25M, F = 64 fp32.
// R1 showed atomics are the limiter (80M fp32 atomics -> 1.25GB WRITE_SIZE,
// 75G atomics/s, 17% HBM). R2: CSR counting-sort (2.5M int atomics) + atomic-
// free register-accumulating gather.

constexpr int FDIM = 64;

// ---------------- CSR build ----------------

__global__ __launch_bounds__(256) void hist_kernel(
    const int* __restrict__ edge0, int* __restrict__ deg, int E) {
    int stride = gridDim.x * blockDim.x;
    for (int e = blockIdx.x * blockDim.x + threadIdx.x; e < E; e += stride)
        atomicAdd(&deg[edge0[e]], 1);
}

// scan pass 1: per-1024-chunk sums
__global__ __launch_bounds__(256) void scan_block_sums(
    const int* __restrict__ deg, int* __restrict__ bsum, int len) {
    __shared__ int lds[4];
    int tid = threadIdx.x, lane = tid & 63, wid = tid >> 6;
    int base = blockIdx.x * 1024 + tid * 4;
    int s = 0;
#pragma unroll
    for (int k = 0; k < 4; ++k) {
        int i = base + k;
        s += (i < len) ? deg[i] : 0;
    }
#pragma unroll
    for (int off = 32; off >= 1; off >>= 1) s += __shfl_down(s, off);
    if (lane == 0) lds[wid] = s;
    __syncthreads();
    if (tid == 0) bsum[blockIdx.x] = lds[0] + lds[1] + lds[2] + lds[3];
}

// scan pass 2: exclusive scan of the (<=512) chunk sums, single block
__global__ __launch_bounds__(256) void scan_partials(int* __restrict__ bsum, int nb) {
    __shared__ int lds[512];
    for (int i = threadIdx.x; i < nb; i += blockDim.x) lds[i] = bsum[i];
    __syncthreads();
    if (threadIdx.x == 0) {
        int run = 0;
        for (int i = 0; i < nb; ++i) { int t = lds[i]; lds[i] = run; run += t; }
    }
    __syncthreads();
    for (int i = threadIdx.x; i < nb; i += blockDim.x) bsum[i] = lds[i];
}

// scan pass 3: per-chunk exclusive scan + chunk offset -> rowptr, cursor
__global__ __launch_bounds__(256) void scan_final(
    const int* __restrict__ deg, const int* __restrict__ bsum,
    int* __restrict__ rowptr, int* __restrict__ cursor, int len, int N) {
    __shared__ int wsum[4];
    int tid = threadIdx.x, lane = tid & 63, wid = tid >> 6;
    int base = blockIdx.x * 1024 + tid * 4;
    int x[4];
#pragma unroll
    for (int k = 0; k < 4; ++k) {
        int i = base + k;
        x[k] = (i < len) ? deg[i] : 0;
    }
    int s = x[0] + x[1] + x[2] + x[3];
    int incl = s;
#pragma unroll
    for (int off = 1; off < 64; off <<= 1) {
        int t = __shfl_up(incl, off);
        if (lane >= off) incl += t;
    }
    if (lane == 63) wsum[wid] = incl;
    __syncthreads();
    if (tid == 0) {
        int run = 0;
#pragma unroll
        for (int w = 0; w < 4; ++w) { int t = wsum[w]; wsum[w] = run; run += t; }
    }
    __syncthreads();
    int run = bsum[blockIdx.x] + wsum[wid] + (incl - s);
#pragma unroll
    for (int k = 0; k < 4; ++k) {
        int i = base + k;
        if (i < len) {
            rowptr[i] = run;
            if (i < N) cursor[i] = run;
            run += x[k];
        }
    }
}

__global__ __launch_bounds__(256) void fill_kernel(
    const int* __restrict__ edge0, int* __restrict__ cursor,
    int* __restrict__ elist, int E) {
    int stride = gridDim.x * blockDim.x;
    for (int e = blockIdx.x * blockDim.x + threadIdx.x; e < E; e += stride) {
        int n = edge0[e];
        int pos = atomicAdd(&cursor[n], 1);
        elist[pos] = e;
    }
}

// ---------------- atomic-free gather ----------------
// 16 threads per node, each owns one float4 (4 features). Register accumulate.
__global__ __launch_bounds__(256) void gather_kernel(
    const int* __restrict__ rowptr, const int* __restrict__ elist,
    const float4* __restrict__ w4, float4* __restrict__ out4, int N) {
    int tid = threadIdx.x;
    int node = blockIdx.x * 16 + (tid >> 4);
    int q = tid & 15;
    if (node >= N) return;
    int s = rowptr[node];
    int t = rowptr[node + 1];
    float4 acc = {0.f, 0.f, 0.f, 0.f};
    for (int j = s; j < t; ++j) {
        int e = elist[j];                       // broadcast across the 16-lane group
        float4 w = w4[(size_t)e * 16 + q];      // 256B contiguous per edge per group
        acc.x += w.x; acc.y += w.y; acc.z += w.z; acc.w += w.w;
    }
    out4[(size_t)node * 16 + q] = acc;          // covers every node -> no out memset
}

// ---------------- R1 fallback (atomic scatter) if ws too small ----------------
__global__ __launch_bounds__(256) void spmm_scatter(
    const int* __restrict__ edge0, const float4* __restrict__ w4,
    float* __restrict__ out, long long total) {
    long long stride = (long long)gridDim.x * blockDim.x;
    for (long long i = (long long)blockIdx.x * blockDim.x + threadIdx.x;
         i < total; i += stride) {
        int e = (int)(i >> 4);
        int q = (int)(i & 15);
        int idx = edge0[e];
        float4 w = w4[i];
        float* p = out + (size_t)idx * FDIM + q * 4;
        unsafeAtomicAdd(p + 0, w.x);
        unsafeAtomicAdd(p + 1, w.y);
        unsafeAtomicAdd(p + 2, w.z);
        unsafeAtomicAdd(p + 3, w.w);
    }
}

extern "C" void kernel_launch(void* const* d_in, const int* in_sizes, int n_in,
                              void* d_out, int out_size, void* d_ws, size_t ws_size,
                              hipStream_t stream) {
    const int* edge = (const int*)d_in[0];        // (2,E) int32; row 0 = dst
    const float* edge_w = (const float*)d_in[1];  // (E,64) fp32
    float* out = (float*)d_out;

    const int E = in_sizes[1] / FDIM;             // 1,250,000
    const int N = out_size / FDIM;                // 100,000
    const int lenDeg = N + 1;
    const int nb = (lenDeg + 1023) / 1024;        // 98 chunks

    // ws layout (ints): deg[N+1] | rowptr[N+1] | cursor[N] | bsum[512] | elist[E]
    size_t need = ((size_t)(3 * (size_t)N + 2 + 512) + (size_t)E) * sizeof(int);
    if (ws_size < need) {
        // fallback: R1 atomic scatter
        hipMemsetAsync(d_out, 0, (size_t)out_size * sizeof(float), stream);
        long long total = (long long)E * (FDIM / 4);
        spmm_scatter<<<4096, 256, 0, stream>>>(edge, (const float4*)edge_w, out, total);
        return;
    }

    int* ws = (int*)d_ws;
    int* deg    = ws;                    // N+1
    int* rowptr = deg + (N + 1);         // N+1
    int* cursor = rowptr + (N + 1);      // N
    int* bsum   = cursor + N;            // 512 (pad)
    int* elist  = bsum + 512;            // E

    // deg must be zeroed every call (ws poisoned 0xAA once, never restored)
    hipMemsetAsync(deg, 0, (size_t)lenDeg * sizeof(int), stream);

    hist_kernel<<<2048, 256, 0, stream>>>(edge, deg, E);
    scan_block_sums<<<nb, 256, 0, stream>>>(deg, bsum, lenDeg);
    scan_partials<<<1, 256, 0, stream>>>(bsum, nb);
    scan_final<<<nb, 256, 0, stream>>>(deg, bsum, rowptr, cursor, lenDeg, N);
    fill_kernel<<<2048, 256, 0, stream>>>(edge, cursor, elist, E);

    const int gblocks = (N + 15) / 16;   // 16 nodes per 256-thread block
    gather_kernel<<<gblocks, 256, 0, stream>>>(rowptr, elist,
                                               (const float4*)edge_w,
                                               (float4*)out, N);
}

// Round 4
// 219.669 us; speedup vs baseline: 4.8680x; 1.1396x over previous
//
#include <hip/hip_runtime.h>

// segment_sum: out[n][64] = sum of edge_w[e][64] over e with edge0[e]==n.
// N = 100K, E = 1.25M, F = 64 fp32.
// R1: atomic scatter -> 1069us (atomic-bound, 1.25GB HBM writes).
// R2: CSR + 16-thread/node gather -> 250us. Gather est. ~160us: latency-bound
//     (dependent elist->w4 chain, 12.5 serial iters).
// R3/R4: wave-per-node gather, 4 edges in flight (chain /4), coalesced elist,
//     nontemporal edge_w loads (via ext_vector_type — HIP float4 rejected),
//     int4 edge0 reads in hist/fill.

constexpr int FDIM = 64;

typedef float f32x4 __attribute__((ext_vector_type(4)));  // native vec for nontemporal

// ---------------- CSR build ----------------

__global__ __launch_bounds__(256) void hist_kernel(
    const int* __restrict__ edge0, int* __restrict__ deg, int E) {
    int stride = gridDim.x * blockDim.x;
    int E4 = E >> 2;
    const int4* e4 = (const int4*)edge0;
    for (int i = blockIdx.x * blockDim.x + threadIdx.x; i < E4; i += stride) {
        int4 v = e4[i];
        atomicAdd(&deg[v.x], 1);
        atomicAdd(&deg[v.y], 1);
        atomicAdd(&deg[v.z], 1);
        atomicAdd(&deg[v.w], 1);
    }
    // tail
    int i = E4 * 4 + (blockIdx.x * blockDim.x + threadIdx.x);
    if (i < E) atomicAdd(&deg[edge0[i]], 1);
}

// scan pass 1: per-1024-chunk sums
__global__ __launch_bounds__(256) void scan_block_sums(
    const int* __restrict__ deg, int* __restrict__ bsum, int len) {
    __shared__ int lds[4];
    int tid = threadIdx.x, lane = tid & 63, wid = tid >> 6;
    int base = blockIdx.x * 1024 + tid * 4;
    int s = 0;
#pragma unroll
    for (int k = 0; k < 4; ++k) {
        int i = base + k;
        s += (i < len) ? deg[i] : 0;
    }
#pragma unroll
    for (int off = 32; off >= 1; off >>= 1) s += __shfl_down(s, off);
    if (lane == 0) lds[wid] = s;
    __syncthreads();
    if (tid == 0) bsum[blockIdx.x] = lds[0] + lds[1] + lds[2] + lds[3];
}

// scan pass 2: exclusive scan of the (<=512) chunk sums, single block
__global__ __launch_bounds__(256) void scan_partials(int* __restrict__ bsum, int nb) {
    __shared__ int lds[512];
    for (int i = threadIdx.x; i < nb; i += blockDim.x) lds[i] = bsum[i];
    __syncthreads();
    if (threadIdx.x == 0) {
        int run = 0;
        for (int i = 0; i < nb; ++i) { int t = lds[i]; lds[i] = run; run += t; }
    }
    __syncthreads();
    for (int i = threadIdx.x; i < nb; i += blockDim.x) bsum[i] = lds[i];
}

// scan pass 3: per-chunk exclusive scan + chunk offset -> rowptr, cursor
__global__ __launch_bounds__(256) void scan_final(
    const int* __restrict__ deg, const int* __restrict__ bsum,
    int* __restrict__ rowptr, int* __restrict__ cursor, int len, int N) {
    __shared__ int wsum[4];
    int tid = threadIdx.x, lane = tid & 63, wid = tid >> 6;
    int base = blockIdx.x * 1024 + tid * 4;
    int x[4];
#pragma unroll
    for (int k = 0; k < 4; ++k) {
        int i = base + k;
        x[k] = (i < len) ? deg[i] : 0;
    }
    int s = x[0] + x[1] + x[2] + x[3];
    int incl = s;
#pragma unroll
    for (int off = 1; off < 64; off <<= 1) {
        int t = __shfl_up(incl, off);
        if (lane >= off) incl += t;
    }
    if (lane == 63) wsum[wid] = incl;
    __syncthreads();
    if (tid == 0) {
        int run = 0;
#pragma unroll
        for (int w = 0; w < 4; ++w) { int t = wsum[w]; wsum[w] = run; run += t; }
    }
    __syncthreads();
    int run = bsum[blockIdx.x] + wsum[wid] + (incl - s);
#pragma unroll
    for (int k = 0; k < 4; ++k) {
        int i = base + k;
        if (i < len) {
            rowptr[i] = run;
            if (i < N) cursor[i] = run;
            run += x[k];
        }
    }
}

__global__ __launch_bounds__(256) void fill_kernel(
    const int* __restrict__ edge0, int* __restrict__ cursor,
    int* __restrict__ elist, int E) {
    int stride = gridDim.x * blockDim.x;
    int E4 = E >> 2;
    const int4* e4 = (const int4*)edge0;
    for (int i = blockIdx.x * blockDim.x + threadIdx.x; i < E4; i += stride) {
        int4 v = e4[i];
        int e = i * 4;
        elist[atomicAdd(&cursor[v.x], 1)] = e;
        elist[atomicAdd(&cursor[v.y], 1)] = e + 1;
        elist[atomicAdd(&cursor[v.z], 1)] = e + 2;
        elist[atomicAdd(&cursor[v.w], 1)] = e + 3;
    }
    int i = E4 * 4 + (blockIdx.x * blockDim.x + threadIdx.x);
    if (i < E) elist[atomicAdd(&cursor[edge0[i]], 1)] = i;
}

// ---------------- atomic-free gather: one wave per node ----------------
// 64 lanes = 4 edge-slots (sub) x 16 quads (q). 4 edges in flight per iter:
// dependent elist->w4 chain is ceil(deg/4) ~ 3 iters instead of 12.5.
__global__ __launch_bounds__(256) void gather_kernel(
    const int* __restrict__ rowptr, const int* __restrict__ elist,
    const f32x4* __restrict__ w4, f32x4* __restrict__ out4, int N) {
    int lane = threadIdx.x & 63;
    int node = blockIdx.x * 4 + (threadIdx.x >> 6);
    if (node >= N) return;
    int sub = lane >> 4;   // 0..3: which edge within the 4-wide slice
    int q = lane & 15;     // float4 slot within the 64-feature row
    int s = rowptr[node];
    int t = rowptr[node + 1];
    f32x4 acc = {0.f, 0.f, 0.f, 0.f};
    for (int j = s + sub; j < t; j += 4) {
        int e = elist[j];                    // coalesced 16B across sub-groups
        const f32x4* p = w4 + (size_t)e * 16 + q;
        f32x4 w = __builtin_nontemporal_load(p);   // zero-reuse stream
        acc += w;
    }
    // reduce across the 4 sub-groups (lanes differing in bits 4 and 5)
#pragma unroll
    for (int m = 16; m <= 32; m <<= 1) {
        acc.x += __shfl_xor(acc.x, m);
        acc.y += __shfl_xor(acc.y, m);
        acc.z += __shfl_xor(acc.z, m);
        acc.w += __shfl_xor(acc.w, m);
    }
    if (sub == 0) out4[(size_t)node * 16 + q] = acc;  // covers all nodes
}

// ---------------- R1 fallback (atomic scatter) if ws too small ----------------
__global__ __launch_bounds__(256) void spmm_scatter(
    const int* __restrict__ edge0, const float4* __restrict__ w4,
    float* __restrict__ out, long long total) {
    long long stride = (long long)gridDim.x * blockDim.x;
    for (long long i = (long long)blockIdx.x * blockDim.x + threadIdx.x;
         i < total; i += stride) {
        int e = (int)(i >> 4);
        int q = (int)(i & 15);
        int idx = edge0[e];
        float4 w = w4[i];
        float* p = out + (size_t)idx * FDIM + q * 4;
        unsafeAtomicAdd(p + 0, w.x);
        unsafeAtomicAdd(p + 1, w.y);
        unsafeAtomicAdd(p + 2, w.z);
        unsafeAtomicAdd(p + 3, w.w);
    }
}

extern "C" void kernel_launch(void* const* d_in, const int* in_sizes, int n_in,
                              void* d_out, int out_size, void* d_ws, size_t ws_size,
                              hipStream_t stream) {
    const int* edge = (const int*)d_in[0];        // (2,E) int32; row 0 = dst
    const float* edge_w = (const float*)d_in[1];  // (E,64) fp32
    float* out = (float*)d_out;

    const int E = in_sizes[1] / FDIM;             // 1,250,000
    const int N = out_size / FDIM;                // 100,000
    const int lenDeg = N + 1;
    const int nb = (lenDeg + 1023) / 1024;        // 98 chunks

    // ws layout (ints): deg[N+1] | rowptr[N+1] | cursor[N] | bsum[512] | elist[E]
    size_t need = ((size_t)(3 * (size_t)N + 2 + 512) + (size_t)E) * sizeof(int);
    if (ws_size < need) {
        (void)hipMemsetAsync(d_out, 0, (size_t)out_size * sizeof(float), stream);
        long long total = (long long)E * (FDIM / 4);
        spmm_scatter<<<4096, 256, 0, stream>>>(edge, (const float4*)edge_w, out, total);
        return;
    }

    int* ws = (int*)d_ws;
    int* deg    = ws;                    // N+1
    int* rowptr = deg + (N + 1);         // N+1
    int* cursor = rowptr + (N + 1);      // N
    int* bsum   = cursor + N;            // 512 (pad)
    int* elist  = bsum + 512;            // E

    (void)hipMemsetAsync(deg, 0, (size_t)lenDeg * sizeof(int), stream);

    hist_kernel<<<2048, 256, 0, stream>>>(edge, deg, E);
    scan_block_sums<<<nb, 256, 0, stream>>>(deg, bsum, lenDeg);
    scan_partials<<<1, 256, 0, stream>>>(bsum, nb);
    scan_final<<<nb, 256, 0, stream>>>(deg, bsum, rowptr, cursor, lenDeg, N);
    fill_kernel<<<2048, 256, 0, stream>>>(edge, cursor, elist, E);

    const int gblocks = (N + 3) / 4;     // one 64-lane wave per node
    gather_kernel<<<gblocks, 256, 0, stream>>>(rowptr, elist,
                                               (const f32x4*)edge_w,
                                               (f32x4*)out, N);
}

// Round 5
// 215.118 us; speedup vs baseline: 4.9710x; 1.0212x over previous
//
#include <hip/hip_runtime.h>

// segment_sum: out[n][64] = sum of edge_w[e][64] over e with edge0[e]==n.
// N = 100K, E = 1.25M, F = 64 fp32.
// R1: atomic scatter -> 1069us (atomic-throughput-bound).
// R2: CSR + 16t/node gather -> 250us.
// R4: wave/node gather -> 220us. Post-mortem: per-wave bytes-in-flight was
//     UNCHANGED (1KB) vs R2 -- gather ~165us = 2.1TB/s, latency-limited
//     equilibrium (waves stall on vmcnt between single w4 loads).
// R5: 2-deep unrolled gather: 2 independent edges per sub per iteration
//     -> 2KB/wave in flight. Build unchanged (controlled comparison).

constexpr int FDIM = 64;

typedef float f32x4 __attribute__((ext_vector_type(4)));

// ---------------- CSR build ----------------

__global__ __launch_bounds__(256) void hist_kernel(
    const int* __restrict__ edge0, int* __restrict__ deg, int E) {
    int stride = gridDim.x * blockDim.x;
    int E4 = E >> 2;
    const int4* e4 = (const int4*)edge0;
    for (int i = blockIdx.x * blockDim.x + threadIdx.x; i < E4; i += stride) {
        int4 v = e4[i];
        atomicAdd(&deg[v.x], 1);
        atomicAdd(&deg[v.y], 1);
        atomicAdd(&deg[v.z], 1);
        atomicAdd(&deg[v.w], 1);
    }
    int i = E4 * 4 + (blockIdx.x * blockDim.x + threadIdx.x);
    if (i < E) atomicAdd(&deg[edge0[i]], 1);
}

__global__ __launch_bounds__(256) void scan_block_sums(
    const int* __restrict__ deg, int* __restrict__ bsum, int len) {
    __shared__ int lds[4];
    int tid = threadIdx.x, lane = tid & 63, wid = tid >> 6;
    int base = blockIdx.x * 1024 + tid * 4;
    int s = 0;
#pragma unroll
    for (int k = 0; k < 4; ++k) {
        int i = base + k;
        s += (i < len) ? deg[i] : 0;
    }
#pragma unroll
    for (int off = 32; off >= 1; off >>= 1) s += __shfl_down(s, off);
    if (lane == 0) lds[wid] = s;
    __syncthreads();
    if (tid == 0) bsum[blockIdx.x] = lds[0] + lds[1] + lds[2] + lds[3];
}

__global__ __launch_bounds__(256) void scan_partials(int* __restrict__ bsum, int nb) {
    __shared__ int lds[512];
    for (int i = threadIdx.x; i < nb; i += blockDim.x) lds[i] = bsum[i];
    __syncthreads();
    if (threadIdx.x == 0) {
        int run = 0;
        for (int i = 0; i < nb; ++i) { int t = lds[i]; lds[i] = run; run += t; }
    }
    __syncthreads();
    for (int i = threadIdx.x; i < nb; i += blockDim.x) bsum[i] = lds[i];
}

__global__ __launch_bounds__(256) void scan_final(
    const int* __restrict__ deg, const int* __restrict__ bsum,
    int* __restrict__ rowptr, int* __restrict__ cursor, int len, int N) {
    __shared__ int wsum[4];
    int tid = threadIdx.x, lane = tid & 63, wid = tid >> 6;
    int base = blockIdx.x * 1024 + tid * 4;
    int x[4];
#pragma unroll
    for (int k = 0; k < 4; ++k) {
        int i = base + k;
        x[k] = (i < len) ? deg[i] : 0;
    }
    int s = x[0] + x[1] + x[2] + x[3];
    int incl = s;
#pragma unroll
    for (int off = 1; off < 64; off <<= 1) {
        int t = __shfl_up(incl, off);
        if (lane >= off) incl += t;
    }
    if (lane == 63) wsum[wid] = incl;
    __syncthreads();
    if (tid == 0) {
        int run = 0;
#pragma unroll
        for (int w = 0; w < 4; ++w) { int t = wsum[w]; wsum[w] = run; run += t; }
    }
    __syncthreads();
    int run = bsum[blockIdx.x] + wsum[wid] + (incl - s);
#pragma unroll
    for (int k = 0; k < 4; ++k) {
        int i = base + k;
        if (i < len) {
            rowptr[i] = run;
            if (i < N) cursor[i] = run;
            run += x[k];
        }
    }
}

__global__ __launch_bounds__(256) void fill_kernel(
    const int* __restrict__ edge0, int* __restrict__ cursor,
    int* __restrict__ elist, int E) {
    int stride = gridDim.x * blockDim.x;
    int E4 = E >> 2;
    const int4* e4 = (const int4*)edge0;
    for (int i = blockIdx.x * blockDim.x + threadIdx.x; i < E4; i += stride) {
        int4 v = e4[i];
        int e = i * 4;
        elist[atomicAdd(&cursor[v.x], 1)] = e;
        elist[atomicAdd(&cursor[v.y], 1)] = e + 1;
        elist[atomicAdd(&cursor[v.z], 1)] = e + 2;
        elist[atomicAdd(&cursor[v.w], 1)] = e + 3;
    }
    int i = E4 * 4 + (blockIdx.x * blockDim.x + threadIdx.x);
    if (i < E) elist[atomicAdd(&cursor[edge0[i]], 1)] = i;
}

// ---------------- gather: wave/node, 2-deep MLP ----------------
// 64 lanes = 4 subs x 16 quads. Each sub walks stride-4 through the node's
// edge list, TWO edges per iteration (independent loads) -> 8 edges = 2KB
// in flight per wave instead of 4 edges/1KB.
__global__ __launch_bounds__(256) void gather_kernel(
    const int* __restrict__ rowptr, const int* __restrict__ elist,
    const f32x4* __restrict__ w4, f32x4* __restrict__ out4, int N) {
    int lane = threadIdx.x & 63;
    int node = blockIdx.x * 4 + (threadIdx.x >> 6);
    if (node >= N) return;
    int sub = lane >> 4;
    int q = lane & 15;
    int s = rowptr[node];
    int t = rowptr[node + 1];
    f32x4 acc0 = {0.f, 0.f, 0.f, 0.f};
    f32x4 acc1 = {0.f, 0.f, 0.f, 0.f};
    int j = s + sub;
    for (; j + 4 < t; j += 8) {
        int e0 = elist[j];        // both elist loads issue together
        int e1 = elist[j + 4];
        f32x4 w0 = __builtin_nontemporal_load(w4 + (size_t)e0 * 16 + q);
        f32x4 w1 = __builtin_nontemporal_load(w4 + (size_t)e1 * 16 + q);
        acc0 += w0;
        acc1 += w1;
    }
    if (j < t) {
        int e0 = elist[j];
        acc0 += __builtin_nontemporal_load(w4 + (size_t)e0 * 16 + q);
    }
    acc0 += acc1;
#pragma unroll
    for (int m = 16; m <= 32; m <<= 1) {
        acc0.x += __shfl_xor(acc0.x, m);
        acc0.y += __shfl_xor(acc0.y, m);
        acc0.z += __shfl_xor(acc0.z, m);
        acc0.w += __shfl_xor(acc0.w, m);
    }
    if (sub == 0) out4[(size_t)node * 16 + q] = acc0;  // covers all nodes
}

// ---------------- R1 fallback if ws too small ----------------
__global__ __launch_bounds__(256) void spmm_scatter(
    const int* __restrict__ edge0, const float4* __restrict__ w4,
    float* __restrict__ out, long long total) {
    long long stride = (long long)gridDim.x * blockDim.x;
    for (long long i = (long long)blockIdx.x * blockDim.x + threadIdx.x;
         i < total; i += stride) {
        int e = (int)(i >> 4);
        int q = (int)(i & 15);
        int idx = edge0[e];
        float4 w = w4[i];
        float* p = out + (size_t)idx * FDIM + q * 4;
        unsafeAtomicAdd(p + 0, w.x);
        unsafeAtomicAdd(p + 1, w.y);
        unsafeAtomicAdd(p + 2, w.z);
        unsafeAtomicAdd(p + 3, w.w);
    }
}

extern "C" void kernel_launch(void* const* d_in, const int* in_sizes, int n_in,
                              void* d_out, int out_size, void* d_ws, size_t ws_size,
                              hipStream_t stream) {
    const int* edge = (const int*)d_in[0];        // (2,E) int32; row 0 = dst
    const float* edge_w = (const float*)d_in[1];  // (E,64) fp32
    float* out = (float*)d_out;

    const int E = in_sizes[1] / FDIM;             // 1,250,000
    const int N = out_size / FDIM;                // 100,000
    const int lenDeg = N + 1;
    const int nb = (lenDeg + 1023) / 1024;

    size_t need = ((size_t)(3 * (size_t)N + 2 + 512) + (size_t)E) * sizeof(int);
    if (ws_size < need) {
        (void)hipMemsetAsync(d_out, 0, (size_t)out_size * sizeof(float), stream);
        long long total = (long long)E * (FDIM / 4);
        spmm_scatter<<<4096, 256, 0, stream>>>(edge, (const float4*)edge_w, out, total);
        return;
    }

    int* ws = (int*)d_ws;
    int* deg    = ws;                    // N+1
    int* rowptr = deg + (N + 1);         // N+1
    int* cursor = rowptr + (N + 1);      // N
    int* bsum   = cursor + N;            // 512 (pad)
    int* elist  = bsum + 512;            // E

    (void)hipMemsetAsync(deg, 0, (size_t)lenDeg * sizeof(int), stream);

    hist_kernel<<<2048, 256, 0, stream>>>(edge, deg, E);
    scan_block_sums<<<nb, 256, 0, stream>>>(deg, bsum, lenDeg);
    scan_partials<<<1, 256, 0, stream>>>(bsum, nb);
    scan_final<<<nb, 256, 0, stream>>>(deg, bsum, rowptr, cursor, lenDeg, N);
    fill_kernel<<<2048, 256, 0, stream>>>(edge, cursor, elist, E);

    const int gblocks = (N + 3) / 4;     // one wave per node
    gather_kernel<<<gblocks, 256, 0, stream>>>(rowptr, elist,
                                               (const f32x4*)edge_w,
                                               (f32x4*)out, N);
}

// Round 6
// 175.840 us; speedup vs baseline: 6.0814x; 1.2234x over previous
//
#include <hip/hip_runtime.h>

// segment_sum: out[n][64] = sum of edge_w[e][64] over e with edge0[e]==n.
// N = 100K, E = 1.25M, F = 64 fp32.
// R1: atomic scatter -> 1069us (atomic wall: 75G f32-atomics/s, 1.25GB writes).
// R2: CSR + gather -> 250us. R4: wave/node -> 220us. R5: 2-deep MLP -> 215us.
//   R5 post-mortem: MLP doubling moved 2% => gather (~165us, 2.2TB/s) is at the
//   random-256B-read throughput wall, not latency-limited. Remaining fat = CSR
//   build (~50us: hist+3 scans+fill+memset).
// R6: fixed-capacity bucket build (C=32 >> Poisson(12.5) tail) + spill list:
//   deletes hist + 3 scan launches. Runtime ws_size branch; CSR path kept as
//   fallback, R1 scatter as last resort.

constexpr int FDIM = 64;
constexpr int BUCKET_C = 32;        // slots per node; P(deg>32 | lambda=12.5) ~ 1e-6
constexpr int SPILL_CAP = 262144;   // 1MB; expected spill ~0-10 edges

typedef float f32x4 __attribute__((ext_vector_type(4)));

// ================= bucket path =================

__global__ __launch_bounds__(256) void bucket_fill(
    const int* __restrict__ edge0, int* __restrict__ cursor,
    int* __restrict__ bucket, int* __restrict__ spill,
    int* __restrict__ spillcnt, int E) {
    int stride = gridDim.x * blockDim.x;
    int E4 = E >> 2;
    const int4* e4 = (const int4*)edge0;
    for (int i = blockIdx.x * blockDim.x + threadIdx.x; i < E4; i += stride) {
        int4 v = e4[i];
        int e = i * 4;
        int nn[4] = {v.x, v.y, v.z, v.w};
#pragma unroll
        for (int k = 0; k < 4; ++k) {
            int n = nn[k];
            int pos = atomicAdd(&cursor[n], 1);
            if (pos < BUCKET_C) bucket[(size_t)n * BUCKET_C + pos] = e + k;
            else {
                int sp = atomicAdd(spillcnt, 1);
                if (sp < SPILL_CAP) spill[sp] = e + k;
            }
        }
    }
    int i = E4 * 4 + (blockIdx.x * blockDim.x + threadIdx.x);
    if (i < E) {
        int n = edge0[i];
        int pos = atomicAdd(&cursor[n], 1);
        if (pos < BUCKET_C) bucket[(size_t)n * BUCKET_C + pos] = i;
        else {
            int sp = atomicAdd(spillcnt, 1);
            if (sp < SPILL_CAP) spill[sp] = i;
        }
    }
}

// wave per node; 4 subs x 16 quads; 2-deep MLP (8 edges / 2KB in flight).
__global__ __launch_bounds__(256) void gather_bucket(
    const int* __restrict__ cursor, const int* __restrict__ bucket,
    const f32x4* __restrict__ w4, f32x4* __restrict__ out4, int N) {
    int lane = threadIdx.x & 63;
    int node = blockIdx.x * 4 + (threadIdx.x >> 6);
    if (node >= N) return;
    int sub = lane >> 4;
    int q = lane & 15;
    int cnt = cursor[node];
    if (cnt > BUCKET_C) cnt = BUCKET_C;
    const int* bl = bucket + (size_t)node * BUCKET_C;
    f32x4 acc0 = {0.f, 0.f, 0.f, 0.f};
    f32x4 acc1 = {0.f, 0.f, 0.f, 0.f};
    int j = sub;
    for (; j + 4 < cnt; j += 8) {
        int e0 = bl[j];
        int e1 = bl[j + 4];
        f32x4 w0 = __builtin_nontemporal_load(w4 + (size_t)e0 * 16 + q);
        f32x4 w1 = __builtin_nontemporal_load(w4 + (size_t)e1 * 16 + q);
        acc0 += w0;
        acc1 += w1;
    }
    if (j < cnt) {
        int e0 = bl[j];
        acc0 += __builtin_nontemporal_load(w4 + (size_t)e0 * 16 + q);
    }
    acc0 += acc1;
#pragma unroll
    for (int m = 16; m <= 32; m <<= 1) {
        acc0.x += __shfl_xor(acc0.x, m);
        acc0.y += __shfl_xor(acc0.y, m);
        acc0.z += __shfl_xor(acc0.z, m);
        acc0.w += __shfl_xor(acc0.w, m);
    }
    if (sub == 0) out4[(size_t)node * 16 + q] = acc0;  // covers all nodes
}

// add spilled edges (expected ~0-10) on top of gathered output
__global__ __launch_bounds__(256) void spill_add(
    const int* __restrict__ spill, const int* __restrict__ spillcnt,
    const int* __restrict__ edge0, const float4* __restrict__ w4,
    float* __restrict__ out) {
    int cnt = *spillcnt;
    if (cnt > SPILL_CAP) cnt = SPILL_CAP;
    int total = cnt * 16;
    int stride = gridDim.x * blockDim.x;
    for (int t = blockIdx.x * blockDim.x + threadIdx.x; t < total; t += stride) {
        int ei = t >> 4, q = t & 15;
        int e = spill[ei];
        int n = edge0[e];
        float4 w = w4[(size_t)e * 16 + q];
        float* p = out + (size_t)n * FDIM + q * 4;
        unsafeAtomicAdd(p + 0, w.x);
        unsafeAtomicAdd(p + 1, w.y);
        unsafeAtomicAdd(p + 2, w.z);
        unsafeAtomicAdd(p + 3, w.w);
    }
}

// ================= CSR fallback path (R5, verified) =================

__global__ __launch_bounds__(256) void hist_kernel(
    const int* __restrict__ edge0, int* __restrict__ deg, int E) {
    int stride = gridDim.x * blockDim.x;
    int E4 = E >> 2;
    const int4* e4 = (const int4*)edge0;
    for (int i = blockIdx.x * blockDim.x + threadIdx.x; i < E4; i += stride) {
        int4 v = e4[i];
        atomicAdd(&deg[v.x], 1);
        atomicAdd(&deg[v.y], 1);
        atomicAdd(&deg[v.z], 1);
        atomicAdd(&deg[v.w], 1);
    }
    int i = E4 * 4 + (blockIdx.x * blockDim.x + threadIdx.x);
    if (i < E) atomicAdd(&deg[edge0[i]], 1);
}

__global__ __launch_bounds__(256) void scan_block_sums(
    const int* __restrict__ deg, int* __restrict__ bsum, int len) {
    __shared__ int lds[4];
    int tid = threadIdx.x, lane = tid & 63, wid = tid >> 6;
    int base = blockIdx.x * 1024 + tid * 4;
    int s = 0;
#pragma unroll
    for (int k = 0; k < 4; ++k) {
        int i = base + k;
        s += (i < len) ? deg[i] : 0;
    }
#pragma unroll
    for (int off = 32; off >= 1; off >>= 1) s += __shfl_down(s, off);
    if (lane == 0) lds[wid] = s;
    __syncthreads();
    if (tid == 0) bsum[blockIdx.x] = lds[0] + lds[1] + lds[2] + lds[3];
}

__global__ __launch_bounds__(256) void scan_partials(int* __restrict__ bsum, int nb) {
    __shared__ int lds[512];
    for (int i = threadIdx.x; i < nb; i += blockDim.x) lds[i] = bsum[i];
    __syncthreads();
    if (threadIdx.x == 0) {
        int run = 0;
        for (int i = 0; i < nb; ++i) { int t = lds[i]; lds[i] = run; run += t; }
    }
    __syncthreads();
    for (int i = threadIdx.x; i < nb; i += blockDim.x) bsum[i] = lds[i];
}

__global__ __launch_bounds__(256) void scan_final(
    const int* __restrict__ deg, const int* __restrict__ bsum,
    int* __restrict__ rowptr, int* __restrict__ cursor, int len, int N) {
    __shared__ int wsum[4];
    int tid = threadIdx.x, lane = tid & 63, wid = tid >> 6;
    int base = blockIdx.x * 1024 + tid * 4;
    int x[4];
#pragma unroll
    for (int k = 0; k < 4; ++k) {
        int i = base + k;
        x[k] = (i < len) ? deg[i] : 0;
    }
    int s = x[0] + x[1] + x[2] + x[3];
    int incl = s;
#pragma unroll
    for (int off = 1; off < 64; off <<= 1) {
        int t = __shfl_up(incl, off);
        if (lane >= off) incl += t;
    }
    if (lane == 63) wsum[wid] = incl;
    __syncthreads();
    if (tid == 0) {
        int run = 0;
#pragma unroll
        for (int w = 0; w < 4; ++w) { int t = wsum[w]; wsum[w] = run; run += t; }
    }
    __syncthreads();
    int run = bsum[blockIdx.x] + wsum[wid] + (incl - s);
#pragma unroll
    for (int k = 0; k < 4; ++k) {
        int i = base + k;
        if (i < len) {
            rowptr[i] = run;
            if (i < N) cursor[i] = run;
            run += x[k];
        }
    }
}

__global__ __launch_bounds__(256) void fill_kernel(
    const int* __restrict__ edge0, int* __restrict__ cursor,
    int* __restrict__ elist, int E) {
    int stride = gridDim.x * blockDim.x;
    int E4 = E >> 2;
    const int4* e4 = (const int4*)edge0;
    for (int i = blockIdx.x * blockDim.x + threadIdx.x; i < E4; i += stride) {
        int4 v = e4[i];
        int e = i * 4;
        elist[atomicAdd(&cursor[v.x], 1)] = e;
        elist[atomicAdd(&cursor[v.y], 1)] = e + 1;
        elist[atomicAdd(&cursor[v.z], 1)] = e + 2;
        elist[atomicAdd(&cursor[v.w], 1)] = e + 3;
    }
    int i = E4 * 4 + (blockIdx.x * blockDim.x + threadIdx.x);
    if (i < E) elist[atomicAdd(&cursor[edge0[i]], 1)] = i;
}

__global__ __launch_bounds__(256) void gather_kernel(
    const int* __restrict__ rowptr, const int* __restrict__ elist,
    const f32x4* __restrict__ w4, f32x4* __restrict__ out4, int N) {
    int lane = threadIdx.x & 63;
    int node = blockIdx.x * 4 + (threadIdx.x >> 6);
    if (node >= N) return;
    int sub = lane >> 4;
    int q = lane & 15;
    int s = rowptr[node];
    int t = rowptr[node + 1];
    f32x4 acc0 = {0.f, 0.f, 0.f, 0.f};
    f32x4 acc1 = {0.f, 0.f, 0.f, 0.f};
    int j = s + sub;
    for (; j + 4 < t; j += 8) {
        int e0 = elist[j];
        int e1 = elist[j + 4];
        f32x4 w0 = __builtin_nontemporal_load(w4 + (size_t)e0 * 16 + q);
        f32x4 w1 = __builtin_nontemporal_load(w4 + (size_t)e1 * 16 + q);
        acc0 += w0;
        acc1 += w1;
    }
    if (j < t) {
        int e0 = elist[j];
        acc0 += __builtin_nontemporal_load(w4 + (size_t)e0 * 16 + q);
    }
    acc0 += acc1;
#pragma unroll
    for (int m = 16; m <= 32; m <<= 1) {
        acc0.x += __shfl_xor(acc0.x, m);
        acc0.y += __shfl_xor(acc0.y, m);
        acc0.z += __shfl_xor(acc0.z, m);
        acc0.w += __shfl_xor(acc0.w, m);
    }
    if (sub == 0) out4[(size_t)node * 16 + q] = acc0;
}

// ================= R1 last-resort =================
__global__ __launch_bounds__(256) void spmm_scatter(
    const int* __restrict__ edge0, const float4* __restrict__ w4,
    float* __restrict__ out, long long total) {
    long long stride = (long long)gridDim.x * blockDim.x;
    for (long long i = (long long)blockIdx.x * blockDim.x + threadIdx.x;
         i < total; i += stride) {
        int e = (int)(i >> 4);
        int q = (int)(i & 15);
        int idx = edge0[e];
        float4 w = w4[i];
        float* p = out + (size_t)idx * FDIM + q * 4;
        unsafeAtomicAdd(p + 0, w.x);
        unsafeAtomicAdd(p + 1, w.y);
        unsafeAtomicAdd(p + 2, w.z);
        unsafeAtomicAdd(p + 3, w.w);
    }
}

extern "C" void kernel_launch(void* const* d_in, const int* in_sizes, int n_in,
                              void* d_out, int out_size, void* d_ws, size_t ws_size,
                              hipStream_t stream) {
    const int* edge = (const int*)d_in[0];        // (2,E) int32; row 0 = dst
    const float* edge_w = (const float*)d_in[1];  // (E,64) fp32
    float* out = (float*)d_out;

    const int E = in_sizes[1] / FDIM;             // 1,250,000
    const int N = out_size / FDIM;                // 100,000

    // ---- bucket path: cursor[N] | spillcnt[64 pad] | spill[SPILL_CAP] | bucket[C*N]
    size_t need_bucket = ((size_t)N + 64 + SPILL_CAP + (size_t)BUCKET_C * N) * sizeof(int);
    if (ws_size >= need_bucket) {
        int* ws = (int*)d_ws;
        int* cursor   = ws;                       // N
        int* spillcnt = cursor + N;               // 1 (+pad 63)
        int* spill    = spillcnt + 64;            // SPILL_CAP
        int* bucket   = spill + SPILL_CAP;        // C*N

        // zero cursor + spillcnt in one memset (bucket contents need no init)
        (void)hipMemsetAsync(cursor, 0, ((size_t)N + 64) * sizeof(int), stream);
        bucket_fill<<<2048, 256, 0, stream>>>(edge, cursor, bucket, spill, spillcnt, E);
        gather_bucket<<<(N + 3) / 4, 256, 0, stream>>>(cursor, bucket,
                                                       (const f32x4*)edge_w,
                                                       (f32x4*)out, N);
        spill_add<<<16, 256, 0, stream>>>(spill, spillcnt, edge,
                                          (const float4*)edge_w, out);
        return;
    }

    // ---- CSR fallback: deg[N+1] | rowptr[N+1] | cursor[N] | bsum[512] | elist[E]
    const int lenDeg = N + 1;
    const int nb = (lenDeg + 1023) / 1024;
    size_t need_csr = ((size_t)(3 * (size_t)N + 2 + 512) + (size_t)E) * sizeof(int);
    if (ws_size < need_csr) {
        (void)hipMemsetAsync(d_out, 0, (size_t)out_size * sizeof(float), stream);
        long long total = (long long)E * (FDIM / 4);
        spmm_scatter<<<4096, 256, 0, stream>>>(edge, (const float4*)edge_w, out, total);
        return;
    }

    int* ws = (int*)d_ws;
    int* deg    = ws;
    int* rowptr = deg + (N + 1);
    int* cursor = rowptr + (N + 1);
    int* bsum   = cursor + N;
    int* elist  = bsum + 512;

    (void)hipMemsetAsync(deg, 0, (size_t)lenDeg * sizeof(int), stream);
    hist_kernel<<<2048, 256, 0, stream>>>(edge, deg, E);
    scan_block_sums<<<nb, 256, 0, stream>>>(deg, bsum, lenDeg);
    scan_partials<<<1, 256, 0, stream>>>(bsum, nb);
    scan_final<<<nb, 256, 0, stream>>>(deg, bsum, rowptr, cursor, lenDeg, N);
    fill_kernel<<<2048, 256, 0, stream>>>(edge, cursor, elist, E);
    gather_kernel<<<(N + 3) / 4, 256, 0, stream>>>(rowptr, elist,
                                                   (const f32x4*)edge_w,
                                                   (f32x4*)out, N);
}